// Round 2
// baseline (408.545 us; speedup 1.0000x reference)
//
#include <hip/hip_runtime.h>
#include <hip/hip_bf16.h>

// Binarized-weight 3x3 conv as implicit GEMM:
//   out[n,o,h,w] = sum_{c,kh,kw} sign(W[o,c,kh,kw]) * x[n,c,h+kh-1,w+kw-1]
// GEMM: D[o][p] = sum_k Wmat[o][k] * B[k][p],  k = (kh*3+kw)*128 + c.
// R4: back to R2's proven 128o x 256px / 4-wave / 2-blocks-per-CU shape
// (VGPR caps occupancy at 2 waves/SIMD; cross-block overlap is the
// latency-hider, per m114). Changes vs R2:
//  - A fragments read DIRECTLY from global (wm is 576 KB, L2-resident;
//    per-lane addr = staged-swizzle identity) -> no A LDS, no A barriers.
//  - B double-buffered; next (cc,kh) window prefetched via glds BEFORE
//    the 3-kw compute phase; ONE barrier per (cc,kh) step. 7 barriers
//    per block vs R2's 42, and every vmcnt(0) drain sits behind ~3.7K
//    cycles of MFMA (T3 2-phase recipe).

typedef short bf16x8 __attribute__((ext_vector_type(8)));
typedef float f32x4 __attribute__((ext_vector_type(4)));

#define XT_ELEMS (32 * 66 * 66 * 128)
#define XT_BYTES (XT_ELEMS * 2)

__device__ __forceinline__ void glds16(const void* g, const void* l) {
    __builtin_amdgcn_global_load_lds(
        (const __attribute__((address_space(1))) void*)g,
        (__attribute__((address_space(3))) void*)l, 16, 0, 0);
}

// weight OIHW fp32 -> Wmat[o][j][c] = sign(w[o][c][j]) as bf16, j = kh*3+kw
__global__ void prep_w_kernel(const float* __restrict__ w,
                              __hip_bfloat16* __restrict__ wm) {
    int tid = blockIdx.x * 256 + threadIdx.x;   // 294912 total, exact grid
    int o = tid / 1152;
    int r = tid - o * 1152;
    int j = r >> 7;
    int c = r & 127;
    float v = w[o * 1152 + c * 9 + j];
    float s = (v > 0.f) ? 1.f : ((v < 0.f) ? -1.f : 0.f);
    wm[tid] = __float2bfloat16(s);
}

// x NCHW fp32 -> x_t[n][h+1][w+1][c] bf16 (66x66 spatial, zero halo).
// Coalesced both ways via LDS bounce; halo zeroing folded in (no memset).
__global__ void transpose_x_kernel(const float* __restrict__ x,
                                   __hip_bfloat16* __restrict__ xt) {
    __shared__ short tl[64 * 130];   // stride 130: +65 banks/row -> 2-way max
    const int t = threadIdx.x;
    const int n = blockIdx.x >> 6;
    const int h = blockIdx.x & 63;
    const float* xp = x + (size_t)n * 524288 + h * 64;
    // phase 1: lanes span w -> 256 B contiguous per wave-load
    for (int i = t; i < 8192; i += 256) {
        int w = i & 63, c = i >> 6;
        tl[w * 130 + c] = (short)__bfloat16_as_ushort(__float2bfloat16(xp[c * 4096 + w]));
    }
    // halo zeroing (disjoint addresses; no barrier needed vs phase 2)
    uint* xtn = (uint*)(xt + (size_t)n * 66 * 66 * 128);
    {
        int row = h + 1;
        if (t < 64)       xtn[(row * 66 + 0) * 64 + t] = 0u;        // col 0
        else if (t < 128) xtn[(row * 66 + 65) * 64 + (t - 64)] = 0u; // col 65
    }
    if (h == 0)  for (int i = t; i < 66 * 64; i += 256) xtn[i] = 0u;                  // row 0
    if (h == 63) for (int i = t; i < 66 * 64; i += 256) xtn[65 * 66 * 64 + i] = 0u;   // row 65
    __syncthreads();
    // phase 2: lanes span c (uint = 2 shorts) -> 256 B contiguous stores
    uint* xo = (uint*)(xt + ((size_t)(n * 66 + h + 1) * 66 + 1) * 128);
    for (int i = t; i < 4096; i += 256) {
        int c2 = i & 63;
        int w = i >> 6;
        xo[w * 64 + c2] = *(const uint*)(tl + w * 130 + c2 * 2);
    }
}

// Block: 128 o x 256 px (4 out rows of one n). 4 waves, each 64o x 128px.
// LDS: Bw dbuf 2 x (4 rows x 66 cells x 64 c) = 67.6 KB. 16B segs
// XOR-swizzled by (cell&7) so ds_read_b128 is conflict-free (R2-measured).
// A read direct from global per fragment (no LDS, no barrier).
__global__ __launch_bounds__(256, 2) void gemm_kernel(
    const __hip_bfloat16* __restrict__ xt,
    const __hip_bfloat16* __restrict__ wm,
    float* __restrict__ out) {
    __shared__ short Bw[2][264 * 64];   // 2 x 33792 B

    const int t = threadIdx.x;
    const int lane = t & 63;
    const int wv = t >> 6;              // 0..3
    const int l15 = lane & 15;
    const int quad = lane >> 4;

    const int bid = blockIdx.x;                       // 0..511
    const int px_blk = (bid & 7) * 64 + (bid >> 3);   // XCD-chunked (512%8==0)
    const int o_blk = blockIdx.y;                     // 0..1
    const int n = px_blk >> 4;
    const int h0 = (px_blk & 15) * 4;

    const int wo = (wv & 1) * 64;       // wave origin in o
    const int wp = (wv >> 1) * 128;     // wave origin in px
    const int wpr = wp >> 6;            // wave px-row origin (0 or 2)

    const short* xtS = (const short*)xt;
    // per-lane A base: o = o_blk*128 + wo + l15 (+i*16), k-seg = quad
    const short* aBase = (const short*)wm +
        (size_t)(o_blk * 128 + wo + l15) * 1152 + quad * 8;

    f32x4 acc[4][8] = {};   // [o frag][px frag]

    // stage B window: rows (h0+kh .. h0+kh+3) x 66 cols x 64 c.
    // 2112 segs = 33 wave-issues (wave-uniform tail guard).
    auto stageB = [&](int buf, int cc, int kh) {
        const short* src = xtS + ((size_t)(n * 66 + h0 + kh) * 66) * 128 + cc;
#pragma unroll
        for (int i = 0; i < 9; ++i) {
            int g = i * 4 + wv;          // 0..35
            if (g < 33) {
                int l = g * 64 + lane;
                int cell = l >> 3, q = l & 7;
                glds16(src + cell * 128 + ((q ^ (cell & 7)) * 8),
                       &Bw[buf][g * 512]);
            }
        }
    };

    // prologue
    stageB(0, 0, 0);
    __syncthreads();

    int buf = 0;
    for (int s = 0; s < 6; ++s) {        // s = (cc, kh)
        const int cc = (s >= 3) ? 64 : 0;
        const int kh = (s >= 3) ? (s - 3) : s;
        // prefetch next window into the other buffer (drained at the
        // barrier AFTER the 3-kw compute phase below)
        if (s + 1 < 6) {
            const int s1 = s + 1;
            stageB(buf ^ 1, (s1 >= 3) ? 64 : 0, (s1 >= 3) ? (s1 - 3) : s1);
        }
#pragma unroll
        for (int kw = 0; kw < 3; ++kw) {
            const int j = kh * 3 + kw;
            const short* ap = aBase + j * 128 + cc;
            bf16x8 a0[4], a1[4];
#pragma unroll
            for (int i = 0; i < 4; ++i)      // kf=0 half: k = cc + quad*8
                a0[i] = *(const bf16x8*)(ap + (size_t)i * 16 * 1152);
#pragma unroll
            for (int i = 0; i < 4; ++i)      // kf=1 half: +32 c
                a1[i] = *(const bf16x8*)(ap + (size_t)i * 16 * 1152 + 32);
#pragma unroll
            for (int kf = 0; kf < 2; ++kf) {
                bf16x8 b[8];
#pragma unroll
                for (int i = 0; i < 8; ++i) {
                    int cell = (wpr + (i >> 2)) * 66 + (i & 3) * 16 + l15 + kw;
                    int seg = (kf * 4 + quad) ^ (cell & 7);
                    b[i] = *(const bf16x8*)(&Bw[buf][cell * 64 + seg * 8]);
                }
#pragma unroll
                for (int i = 0; i < 4; ++i)
#pragma unroll
                    for (int jj = 0; jj < 8; ++jj)
                        acc[i][jj] = __builtin_amdgcn_mfma_f32_16x16x32_bf16(
                            kf ? a1[i] : a0[i], b[jj], acc[i][jj], 0, 0, 0);
            }
        }
        __syncthreads();   // drains prefetch (issued a full compute phase ago)
        buf ^= 1;
    }

    // Epilogue: C/D layout col=lane&15 (px), row=quad*4+reg (o)
    const int Pbase = px_blk * 256 + wp;
#pragma unroll
    for (int i = 0; i < 4; ++i) {
#pragma unroll
        for (int jj = 0; jj < 8; ++jj) {
            const int P = Pbase + jj * 16 + l15;
            const int hw = P & 4095;
            float* op = out + (size_t)n * 1048576 + hw;
#pragma unroll
            for (int r = 0; r < 4; ++r) {
                const int o = o_blk * 128 + wo + i * 16 + quad * 4 + r;
                op[(size_t)o * 4096] = acc[i][jj][r];
            }
        }
    }
}

extern "C" void kernel_launch(void* const* d_in, const int* in_sizes, int n_in,
                              void* d_out, int out_size, void* d_ws, size_t ws_size,
                              hipStream_t stream) {
    const float* x = (const float*)d_in[0];
    const float* w = (const float*)d_in[1];
    float* out = (float*)d_out;
    __hip_bfloat16* xt = (__hip_bfloat16*)d_ws;
    __hip_bfloat16* wm = (__hip_bfloat16*)((char*)d_ws + XT_BYTES);

    prep_w_kernel<<<1152, 256, 0, stream>>>(w, wm);
    transpose_x_kernel<<<2048, 256, 0, stream>>>(x, xt);
    gemm_kernel<<<dim3(512, 2), 256, 0, stream>>>(xt, wm, out);
}

// Round 3
// 396.592 us; speedup vs baseline: 1.0301x; 1.0301x over previous
//
#include <hip/hip_runtime.h>
#include <hip/hip_bf16.h>

// Binarized-weight 3x3 conv as implicit GEMM:
//   out[n,o,h,w] = sum_{c,kh,kw} sign(W[o,c,kh,kw]) * x[n,c,h+kh-1,w+kw-1]
// GEMM: D[o][p] = sum_k Wmat[o][k] * B[k][p],  k = (kh*3+kw)*128 + c.
// R5 = m201-style T3+T4 schedule: 512 thr (8 waves, full 256 o -> B staged
// once per block), A and B double-buffered in LDS, counted vmcnt (never 0
// in steady state), two raw barriers per kw-phase, setprio around MFMA.
// All staging traffic stays in the glds/vmcnt domain (R4 lesson: mixing
// reg-dest global loads behind glds prefetch forces full drains).
// 18 phases; per phase: 4 A-glds (+5 B-glds at kw==2), vmcnt(4|9),
// barrier, 24 ds_read_b128, 64 MFMA, barrier.

typedef short bf16x8 __attribute__((ext_vector_type(8)));
typedef float f32x4 __attribute__((ext_vector_type(4)));

#define XT_ELEMS (32 * 66 * 66 * 128)
#define XT_BYTES (XT_ELEMS * 2)

#define VMW4 asm volatile("s_waitcnt vmcnt(4)" ::: "memory")
#define VMW9 asm volatile("s_waitcnt vmcnt(9)" ::: "memory")
#define VMW0 asm volatile("s_waitcnt vmcnt(0)" ::: "memory")
#define BAR()                                  \
    do {                                       \
        asm volatile("" ::: "memory");         \
        __builtin_amdgcn_s_barrier();          \
        asm volatile("" ::: "memory");         \
    } while (0)

__device__ __forceinline__ void glds16(const void* g, const void* l) {
    __builtin_amdgcn_global_load_lds(
        (const __attribute__((address_space(1))) void*)g,
        (__attribute__((address_space(3))) void*)l, 16, 0, 0);
}

// weight OIHW fp32 -> Wmat[o][j][c] = sign(w[o][c][j]) as bf16, j = kh*3+kw
__global__ void prep_w_kernel(const float* __restrict__ w,
                              __hip_bfloat16* __restrict__ wm) {
    int tid = blockIdx.x * 256 + threadIdx.x;   // 294912 total, exact grid
    int o = tid / 1152;
    int r = tid - o * 1152;
    int j = r >> 7;
    int c = r & 127;
    float v = w[o * 1152 + c * 9 + j];
    float s = (v > 0.f) ? 1.f : ((v < 0.f) ? -1.f : 0.f);
    wm[tid] = __float2bfloat16(s);
}

// x NCHW fp32 -> x_t[n][h+1][w+1][c] bf16 (66x66 spatial, zero halo).
__global__ void transpose_x_kernel(const float* __restrict__ x,
                                   __hip_bfloat16* __restrict__ xt) {
    __shared__ short tl[64 * 130];   // stride 130: +65 banks/row -> 2-way max
    const int t = threadIdx.x;
    const int n = blockIdx.x >> 6;
    const int h = blockIdx.x & 63;
    const float* xp = x + (size_t)n * 524288 + h * 64;
    for (int i = t; i < 8192; i += 256) {
        int w = i & 63, c = i >> 6;
        tl[w * 130 + c] = (short)__bfloat16_as_ushort(__float2bfloat16(xp[c * 4096 + w]));
    }
    uint* xtn = (uint*)(xt + (size_t)n * 66 * 66 * 128);
    {
        int row = h + 1;
        if (t < 64)       xtn[(row * 66 + 0) * 64 + t] = 0u;
        else if (t < 128) xtn[(row * 66 + 65) * 64 + (t - 64)] = 0u;
    }
    if (h == 0)  for (int i = t; i < 66 * 64; i += 256) xtn[i] = 0u;
    if (h == 63) for (int i = t; i < 66 * 64; i += 256) xtn[65 * 66 * 64 + i] = 0u;
    __syncthreads();
    uint* xo = (uint*)(xt + ((size_t)(n * 66 + h + 1) * 66 + 1) * 128);
    for (int i = t; i < 4096; i += 256) {
        int c2 = i & 63;
        int w = i >> 6;
        xo[w * 64 + c2] = *(const uint*)(tl + w * 130 + c2 * 2);
    }
}

// Block: 256 o x 256 px (4 out rows of one n). 8 waves = 4(o) x 2(px),
// each wave 64o x 128px. LDS 130 KB: As dbuf 2x[256 o][64 c] (32 KB ea),
// Bw dbuf 2x[4x66 cells][64 c] (33 KB ea). 16B segs XOR-swizzled by
// (o&7)/(cell&7): all ds_read_b128 2-way max (R2-measured 0 conflicts).
__global__ __launch_bounds__(512, 2) void gemm_kernel(
    const __hip_bfloat16* __restrict__ xt,
    const __hip_bfloat16* __restrict__ wm,
    float* __restrict__ out) {
    __shared__ short As[2][256 * 64];   // 2 x 32768 B
    __shared__ short Bw[2][264 * 64];   // 2 x 33792 B

    const int t = threadIdx.x;
    const int lane = t & 63;
    const int wv = t >> 6;              // 0..7
    const int l15 = lane & 15;
    const int quad = lane >> 4;

    const int bid = blockIdx.x;                       // 0..511
    const int px_blk = (bid & 7) * 64 + (bid >> 3);   // XCD-chunked (512%8==0)
    const int n = px_blk >> 4;
    const int h0 = (px_blk & 15) * 4;

    const int wo = (wv >> 1) * 64;      // wave o origin: 0/64/128/192
    const int wpr = (wv & 1) * 2;       // wave px-row origin: 0 or 2

    const short* wmS = (const short*)wm;
    const short* xtS = (const short*)xt;

    f32x4 acc[4][8] = {};   // [o frag][px frag]

    // stage A chunk: 256 o x 64 c for (cc, j). 2048 segs = 4 issues/wave.
    auto stageA = [&](int pa, int cc, int j) {
#pragma unroll
        for (int i = 0; i < 4; ++i) {
            int g = i * 8 + wv;          // 0..31, uniform 4/wave
            int l = g * 64 + lane;
            int o = l >> 3, q = l & 7;
            glds16(wmS + o * 1152 + j * 128 + cc + ((q ^ (o & 7)) * 8),
                   &As[pa][g * 512]);
        }
    };
    // stage B window: rows (h0+kh..h0+kh+3) x 66 cols x 64 c. 2112 segs =
    // 33 blocks; 5 uniform issues/wave (i==4 clamps to seg-block 32: all
    // waves re-write the same data to the same dest -> benign, keeps
    // per-wave vmcnt counts identical).
    auto stageB = [&](int pb, int cc, int kh) {
        const short* src = xtS + ((size_t)(n * 66 + h0 + kh) * 66) * 128 + cc;
#pragma unroll
        for (int i = 0; i < 5; ++i) {
            int g = i * 8 + wv;
            if (g > 32) g = 32;
            int l = g * 64 + lane;
            int cell = l >> 3, q = l & 7;
            glds16(src + cell * 128 + ((q ^ (cell & 7)) * 8),
                   &Bw[pb][g * 512]);
        }
    };

    // prologue: stage step 0 (9 issues in flight; drained by p0's VMW4)
    stageB(0, 0, 0);
    stageA(0, 0, 0);

    int pa = 0, pb = 0;
    for (int s = 0; s < 6; ++s) {
        const int cc = (s >= 3) ? 64 : 0;
        const int kh = (s >= 3) ? (s - 3) : s;
        const int sn = s + 1;
        const int ccn = (sn >= 3) ? 64 : 0;
        const int khn = (sn >= 3) ? (sn - 3) : sn;   // s==5: unused (guarded)
#pragma unroll
        for (int kw = 0; kw < 3; ++kw) {
            // --- issue next phase's staging (stays in flight across BAR)
            if (kw < 2) {
                stageA(pa ^ 1, cc, kh * 3 + kw + 1);
                VMW4;           // drain prev phase's 4 A (FIFO: oldest first)
            } else if (s < 5) {
                stageA(pa ^ 1, ccn, khn * 3);
                stageB(pb ^ 1, ccn, khn);
                VMW9;           // drain prev 4 A; leave current 4A+5B in flight
            } else {
                VMW0;           // tail: complete last A
            }
            BAR();
            // --- compute (cc, kh, kw) from As[pa], Bw[pb]
#pragma unroll
            for (int kf = 0; kf < 2; ++kf) {
                bf16x8 a[4], b[8];
#pragma unroll
                for (int i = 0; i < 4; ++i) {
                    int o = wo + i * 16 + l15;
                    a[i] = *(const bf16x8*)(
                        &As[pa][o * 64 + (((kf * 4 + quad) ^ (o & 7)) * 8)]);
                }
#pragma unroll
                for (int i = 0; i < 8; ++i) {
                    int cell = (wpr + (i >> 2)) * 66 + (i & 3) * 16 + l15 + kw;
                    int seg = (kf * 4 + quad) ^ (cell & 7);
                    b[i] = *(const bf16x8*)(&Bw[pb][cell * 64 + seg * 8]);
                }
                __builtin_amdgcn_s_setprio(1);
#pragma unroll
                for (int i = 0; i < 4; ++i)
#pragma unroll
                    for (int jj = 0; jj < 8; ++jj)
                        acc[i][jj] = __builtin_amdgcn_mfma_f32_16x16x32_bf16(
                            a[i], b[jj], acc[i][jj], 0, 0, 0);
                __builtin_amdgcn_s_setprio(0);
            }
            BAR();   // all waves' ds_reads done before anyone issues next glds
            pa ^= 1;
        }
        pb ^= 1;
    }

    // Epilogue: C/D layout col=lane&15 (px), row=quad*4+reg (o)
    const int Pbase = px_blk * 256 + (wv & 1) * 128;
#pragma unroll
    for (int i = 0; i < 4; ++i) {
#pragma unroll
        for (int jj = 0; jj < 8; ++jj) {
            const int P = Pbase + jj * 16 + l15;
            const int hw = P & 4095;
            float* op = out + (size_t)n * 1048576 + hw;
#pragma unroll
            for (int r = 0; r < 4; ++r) {
                const int o = wo + i * 16 + quad * 4 + r;
                op[(size_t)o * 4096] = acc[i][jj][r];
            }
        }
    }
}

extern "C" void kernel_launch(void* const* d_in, const int* in_sizes, int n_in,
                              void* d_out, int out_size, void* d_ws, size_t ws_size,
                              hipStream_t stream) {
    const float* x = (const float*)d_in[0];
    const float* w = (const float*)d_in[1];
    float* out = (float*)d_out;
    __hip_bfloat16* xt = (__hip_bfloat16*)d_ws;
    __hip_bfloat16* wm = (__hip_bfloat16*)((char*)d_ws + XT_BYTES);

    prep_w_kernel<<<1152, 256, 0, stream>>>(w, wm);
    transpose_x_kernel<<<2048, 256, 0, stream>>>(x, xt);
    gemm_kernel<<<512, 512, 0, stream>>>(xt, wm, out);
}